// Round 10
// baseline (285.592 us; speedup 1.0000x reference)
//
#include <hip/hip_runtime.h>
#include <hip/hip_bf16.h>

#define F_IN 512
#define NB 128              // dst nodes per bucket
#define SRC_BITS 17         // N <= 131072
#define SRC_MASK ((1 << SRC_BITS) - 1)
#define T_APP 16384         // edges per chunk
#define PSTRIDE 800         // pcount row stride (>= nb)
#define BCAP 5120           // bsort LDS cache capacity (edges per bucket)
#define LOG2E 1.4426950408889634f

typedef unsigned int uint;
typedef unsigned short ushort;

__device__ __forceinline__ uint f2bf(float f) {
  uint u = __float_as_uint(f);
  return (u + 0x7fffu + ((u >> 16) & 1u)) >> 16;  // RNE
}
__device__ __forceinline__ float bflo(uint u) { return __uint_as_float(u << 16); }
__device__ __forceinline__ float bfhi(uint u) { return __uint_as_float(u & 0xffff0000u); }

// ---------------- lin1: h0 = relu(x @ W1^T + b1) -> bf16 rows ----------------
__global__ __launch_bounds__(256) void lin1_kernel(
    const float* __restrict__ x, const float* __restrict__ w1,
    const float* __restrict__ b1, uint* __restrict__ h0b, int N) {
  __shared__ float sW[16 * F_IN];
  for (int i = threadIdx.x; i < 16 * F_IN / 4; i += 256)
    ((float4*)sW)[i] = ((const float4*)w1)[i];
  __syncthreads();

  int wave = (blockIdx.x * 256 + threadIdx.x) >> 6;
  int lane = threadIdx.x & 63;
  int j = lane & 15;
  int g = lane >> 4;
  int node = wave * 4 + g;
  if (node >= N) return;

  const float4* xr = (const float4*)(x + (size_t)node * F_IN);
  float acc[16];
#pragma unroll
  for (int k = 0; k < 16; ++k) acc[k] = 0.f;

#pragma unroll
  for (int t = 0; t < 8; ++t) {
    float4 xv = xr[t * 16 + j];
#pragma unroll
    for (int k = 0; k < 16; ++k) {
      float4 wv = *(const float4*)&sW[k * F_IN + t * 64 + j * 4];
      acc[k] = fmaf(xv.x, wv.x, fmaf(xv.y, wv.y, fmaf(xv.z, wv.z, fmaf(xv.w, wv.w, acc[k]))));
    }
  }
#pragma unroll
  for (int s = 1; s < 16; s <<= 1) {
#pragma unroll
    for (int k = 0; k < 16; ++k) acc[k] += __shfl_xor(acc[k], s, 64);
  }
  float hv = 0.f;
#pragma unroll
  for (int k = 0; k < 16; ++k)
    if (j == k) hv = acc[k];
  hv += b1[j];
  hv = fmaxf(hv, 0.f);

  float hp = __shfl_xor(hv, 1, 64);  // partner feature (j^1)
  if (!(j & 1))                      // even j packs (j, j+1)
    h0b[(size_t)node * 8 + (j >> 1)] = f2bf(hv) | (f2bf(hp) << 16);
}

// ---------------- edge build: rank-caching two-level counting sort ----------------
// Pass 1: per-chunk bucket hist; atomicAdd's RETURN VALUE is the edge's rank
// within (chunk, bucket) — stored once, removes all later ranking atomics.
__global__ __launch_bounds__(512) void brank_kernel(
    const int* __restrict__ dst, ushort* __restrict__ rank16,
    int* __restrict__ pcount, int E, int nb) {
  __shared__ int hist[1024];
  int t = threadIdx.x;
  for (int i = t; i < nb; i += 512) hist[i] = 0;
  __syncthreads();
  int e0 = blockIdx.x * T_APP, e1 = min(E, e0 + T_APP);
  for (int i = e0 + t; i < e1; i += 512) {
    int r = atomicAdd(&hist[dst[i] >> 7], 1);
    rank16[i] = (ushort)r;
  }
  __syncthreads();
  int* row = pcount + (size_t)blockIdx.x * PSTRIDE;
  for (int i = t; i < nb; i += 512) row[i] = hist[i];
}

// Pass 2: in-place per-bucket prefix over chunks + bucket exclusive scan.
__global__ __launch_bounds__(1024) void bscan_kernel(
    int* __restrict__ pcount, int* __restrict__ boff, int* __restrict__ bcount,
    int* __restrict__ offg, int N, int nb, int nch, int E) {
  __shared__ int s[1024];
  int t = threadIdx.x;
  int run = 0;
  if (t < nb) {
    for (int b = 0; b < nch; ++b) {
      size_t idx = (size_t)b * PSTRIDE + t;
      int v = pcount[idx];
      pcount[idx] = run;   // prefix of this bucket over earlier chunks
      run += v;
    }
  }
  s[t] = run;
  __syncthreads();
  for (int st = 1; st < 1024; st <<= 1) {
    int a = (t >= st) ? s[t - st] : 0;
    __syncthreads();
    s[t] += a;
    __syncthreads();
  }
  if (t < nb) {
    boff[t] = s[t] - run;
    bcount[t] = run;
  }
  if (t == 0) offg[N] = E;
}

// Pass 3: atomic-free scatter — slot fully determined by (boff, chunk-prefix, rank).
__global__ __launch_bounds__(512) void bscat_kernel(
    const int* __restrict__ src, const int* __restrict__ dst,
    const ushort* __restrict__ rank16, const int* __restrict__ pcount,
    const int* __restrict__ boff, int* __restrict__ elist, int E, int nb) {
  __shared__ int srow[1024];
  int t = threadIdx.x;
  const int* row = pcount + (size_t)blockIdx.x * PSTRIDE;
  for (int i = t; i < nb; i += 512) srow[i] = boff[i] + row[i];
  __syncthreads();
  int e0 = blockIdx.x * T_APP, e1 = min(E, e0 + T_APP);
  for (int i = e0 + t; i < e1; i += 512) {
    int d = dst[i];
    int slot = srow[d >> 7] + (int)rank16[i];
    elist[slot] = src[i] | ((d & (NB - 1)) << SRC_BITS);
  }
}

// Pass 4: one block per bucket — node-level counting sort, rank cached in LDS
// (single atomic pass; statistically-unreachable fallback keeps correctness).
__global__ __launch_bounds__(256) void bsort_kernel(
    const int* __restrict__ elist, const int* __restrict__ boff,
    const int* __restrict__ bcount, int* __restrict__ csr,
    int* __restrict__ offg, int N) {
  __shared__ int hist[NB], scn[NB], cur[NB];
  __shared__ int spk[BCAP];
  __shared__ ushort lrank[BCAP];
  int b = blockIdx.x, t = threadIdx.x;
  int base = boff[b], cnt = bcount[b];
  int node0 = b * NB, nn = min(NB, N - node0);
  bool cached = (cnt <= BCAP);
  if (t < NB) hist[t] = 0;
  __syncthreads();
  for (int i = t; i < cnt; i += 256) {
    int pk = elist[base + i];
    int ld = pk >> SRC_BITS;
    int r = atomicAdd(&hist[ld], 1);
    if (cached) { spk[i] = pk; lrank[i] = (ushort)r; }
  }
  __syncthreads();
  if (t < NB) scn[t] = hist[t];
  __syncthreads();
  for (int st = 1; st < NB; st <<= 1) {
    int v = (t >= st && t < NB) ? scn[t - st] : 0;
    __syncthreads();
    if (t < NB) scn[t] += v;
    __syncthreads();
  }
  if (t < NB) {
    int ex = scn[t] - hist[t];
    cur[t] = ex;
    scn[t] = ex;  // now exclusive
    if (t < nn) offg[node0 + t] = base + ex;
  }
  __syncthreads();
  if (cached) {
    for (int i = t; i < cnt; i += 256) {
      int pk = spk[i];
      int ld = pk >> SRC_BITS;
      csr[base + scn[ld] + (int)lrank[i]] = pk & SRC_MASK;
    }
  } else {
    for (int i = t; i < cnt; i += 256) {
      int pk = elist[base + i];
      int ld = pk >> SRC_BITS;
      int slot = atomicAdd(&cur[ld], 1);
      csr[base + slot] = pk & SRC_MASK;
    }
  }
}

// ---------------- AGNN propagation: wave per dst node, 16 edge-slots x 4 lanes ----------
// (unchanged from round 9)
template <bool LAST>
__global__ __launch_bounds__(256) void prop_kernel(
    const uint2* __restrict__ hb, const int* __restrict__ off,
    const int* __restrict__ csr, const float* __restrict__ beta_ptr,
    uint2* __restrict__ houtb, float* __restrict__ hout32, int N) {
  int d = (blockIdx.x * 256 + threadIdx.x) >> 6;
  int lane = threadIdx.x & 63;
  int p = lane & 3;       // feature quad
  int slot = lane >> 2;   // 16 edge slots
  if (d >= N) return;

  float beta = beta_ptr ? beta_ptr[0] : 1.0f;
  uint2 hdu = hb[(size_t)d * 4 + p];
  float hd0 = bflo(hdu.x), hd1 = bfhi(hdu.x), hd2 = bflo(hdu.y), hd3 = bfhi(hdu.y);

  float ssd = fmaf(hd0, hd0, fmaf(hd1, hd1, fmaf(hd2, hd2, hd3 * hd3)));
  ssd += __shfl_xor(ssd, 1, 64);
  ssd += __shfl_xor(ssd, 2, 64);
  float rnd = rsqrtf(fmaxf(ssd, 1e-24f));
  float brnl2d = beta * LOG2E * rnd;

  float den = 0.f, n0 = 0.f, n1 = 0.f, n2 = 0.f, n3 = 0.f;
  if (slot == 0) {
    float es = exp2f(beta * LOG2E);    // self-loop: cos = 1
    den = es;
    n0 = es * hd0; n1 = es * hd1; n2 = es * hd2; n3 = es * hd3;
  }

  int base = off[d];
  int dg = off[d + 1] - base;
  for (int i = slot; i < dg; i += 32) {
    int i1 = i + 16;
    bool v1 = i1 < dg;
    int s0 = csr[base + i];
    int s1 = v1 ? csr[base + i1] : s0;
    uint2 au = hb[(size_t)s0 * 4 + p];
    uint2 bu = hb[(size_t)s1 * 4 + p];
    float a0 = bflo(au.x), a1 = bfhi(au.x), a2 = bflo(au.y), a3 = bfhi(au.y);
    float c0 = bflo(bu.x), c1 = bfhi(bu.x), c2 = bflo(bu.y), c3 = bfhi(bu.y);
    float dt0 = fmaf(a0, hd0, fmaf(a1, hd1, fmaf(a2, hd2, a3 * hd3)));
    float dt1 = fmaf(c0, hd0, fmaf(c1, hd1, fmaf(c2, hd2, c3 * hd3)));
    float ss0 = fmaf(a0, a0, fmaf(a1, a1, fmaf(a2, a2, a3 * a3)));
    float ss1 = fmaf(c0, c0, fmaf(c1, c1, fmaf(c2, c2, c3 * c3)));
    dt0 += __shfl_xor(dt0, 1, 64);
    dt1 += __shfl_xor(dt1, 1, 64);
    ss0 += __shfl_xor(ss0, 1, 64);
    ss1 += __shfl_xor(ss1, 1, 64);
    dt0 += __shfl_xor(dt0, 2, 64);
    dt1 += __shfl_xor(dt1, 2, 64);
    ss0 += __shfl_xor(ss0, 2, 64);
    ss1 += __shfl_xor(ss1, 2, 64);
    float rs0 = rsqrtf(fmaxf(ss0, 1e-24f));
    float rs1 = rsqrtf(fmaxf(ss1, 1e-24f));
    float e0 = exp2f(dt0 * rs0 * brnl2d);
    float e1 = exp2f(dt1 * rs1 * brnl2d);
    e1 = v1 ? e1 : 0.f;
    den += e0 + e1;
    n0 = fmaf(e1, c0, fmaf(e0, a0, n0));
    n1 = fmaf(e1, c1, fmaf(e0, a1, n1));
    n2 = fmaf(e1, c2, fmaf(e0, a2, n2));
    n3 = fmaf(e1, c3, fmaf(e0, a3, n3));
  }
#pragma unroll
  for (int st = 4; st < 64; st <<= 1) {
    den += __shfl_xor(den, st, 64);
    n0 += __shfl_xor(n0, st, 64);
    n1 += __shfl_xor(n1, st, 64);
    n2 += __shfl_xor(n2, st, 64);
    n3 += __shfl_xor(n3, st, 64);
  }
  float inv = 1.f / den;
  float o0 = n0 * inv, o1 = n1 * inv, o2 = n2 * inv, o3 = n3 * inv;

  if (LAST) {
    if (slot == 0)
      *(float4*)&hout32[(size_t)d * 16 + 4 * p] = make_float4(o0, o1, o2, o3);
  } else {
    if (slot == 0) {
      uint2 w;
      w.x = f2bf(o0) | (f2bf(o1) << 16);
      w.y = f2bf(o2) | (f2bf(o3) << 16);
      houtb[(size_t)d * 4 + p] = w;
    }
  }
}

// ---------------- lin2 + log_softmax: one thread per node ----------------
__global__ __launch_bounds__(256) void lin2_kernel(
    const float* __restrict__ h2, const float* __restrict__ w2,
    const float* __restrict__ b2, float* __restrict__ out, int N) {
  __shared__ float sw2[256];  // w2[c*16+m]
  __shared__ float sb2[16];
  if (threadIdx.x < 256) sw2[threadIdx.x] = w2[threadIdx.x];
  if (threadIdx.x < 16) sb2[threadIdx.x] = b2[threadIdx.x];
  __syncthreads();

  int n = blockIdx.x * 256 + threadIdx.x;
  if (n >= N) return;

  float h[16];
  const float4* hr = (const float4*)(h2 + (size_t)n * 16);
#pragma unroll
  for (int q = 0; q < 4; ++q) {
    float4 v = hr[q];
    h[4 * q + 0] = v.x; h[4 * q + 1] = v.y; h[4 * q + 2] = v.z; h[4 * q + 3] = v.w;
  }
  float lg[16], mx = -1e30f;
#pragma unroll
  for (int c = 0; c < 16; ++c) {
    float a = sb2[c];
#pragma unroll
    for (int m = 0; m < 16; ++m) a = fmaf(h[m], sw2[c * 16 + m], a);
    lg[c] = a;
    mx = fmaxf(mx, a);
  }
  float sm = 0.f;
#pragma unroll
  for (int c = 0; c < 16; ++c) sm += __expf(lg[c] - mx);
  float ls = mx + logf(sm);
  float4* orow = (float4*)(out + (size_t)n * 16);
#pragma unroll
  for (int q = 0; q < 4; ++q)
    orow[q] = make_float4(lg[4 * q + 0] - ls, lg[4 * q + 1] - ls,
                          lg[4 * q + 2] - ls, lg[4 * q + 3] - ls);
}

extern "C" void kernel_launch(void* const* d_in, const int* in_sizes, int n_in,
                              void* d_out, int out_size, void* d_ws, size_t ws_size,
                              hipStream_t stream) {
  const float* x     = (const float*)d_in[0];
  const int*   ei    = (const int*)d_in[1];
  const float* w1    = (const float*)d_in[2];
  const float* b1    = (const float*)d_in[3];
  const float* w2    = (const float*)d_in[4];
  const float* b2    = (const float*)d_in[5];
  const float* beta2 = (const float*)d_in[6];
  float* out = (float*)d_out;

  const int N = in_sizes[0] / F_IN;   // 100000
  const int E = in_sizes[1] / 2;      // 3200000
  const int* src = ei;
  const int* dst = ei + E;
  const int nb = (N + NB - 1) / NB;   // 782
  const int nch = (E + T_APP - 1) / T_APP;  // 196

  char* ws = (char*)d_ws;
  size_t wo = 0;
  auto take = [&](size_t bytes) -> void* {
    void* p = ws + wo;
    wo = (wo + bytes + 255) & ~(size_t)255;
    return p;
  };
  int*    pcount = (int*)take((size_t)nch * PSTRIDE * 4);
  int*    bcount = (int*)take((size_t)nb * 4);
  int*    boff   = (int*)take((size_t)nb * 4);
  int*    offg   = (int*)take((size_t)(N + 1) * 4);
  ushort* rank16 = (ushort*)take((size_t)E * 2);
  int*    csr    = (int*)take((size_t)E * 4);
  int*    elist  = (int*)take((size_t)E * 4);  // dead after bsort; h1b aliases it
  uint*   h0b    = (uint*)take((size_t)N * 8 * 4);
  float*  h2     = (float*)take((size_t)N * 16 * 4);
  uint*   h1b    = (uint*)(elist);             // alias (elist dead before prop1)

  lin1_kernel<<<(N + 15) / 16, 256, 0, stream>>>(x, w1, b1, h0b, N);

  brank_kernel<<<nch, 512, 0, stream>>>(dst, rank16, pcount, E, nb);
  bscan_kernel<<<1, 1024, 0, stream>>>(pcount, boff, bcount, offg, N, nb, nch, E);
  bscat_kernel<<<nch, 512, 0, stream>>>(src, dst, rank16, pcount, boff, elist, E, nb);
  bsort_kernel<<<nb, 256, 0, stream>>>(elist, boff, bcount, csr, offg, N);

  prop_kernel<false><<<(N + 3) / 4, 256, 0, stream>>>(
      (const uint2*)h0b, offg, csr, nullptr, (uint2*)h1b, nullptr, N);
  prop_kernel<true><<<(N + 3) / 4, 256, 0, stream>>>(
      (const uint2*)h1b, offg, csr, beta2, nullptr, h2, N);
  lin2_kernel<<<(N + 255) / 256, 256, 0, stream>>>(h2, w2, b2, out, N);
}

// Round 11
// 270.209 us; speedup vs baseline: 1.0569x; 1.0569x over previous
//
#include <hip/hip_runtime.h>
#include <hip/hip_bf16.h>

#define F_IN 512
#define NB 128              // dst nodes per bucket
#define SRC_BITS 17         // N <= 131072
#define SRC_MASK ((1 << SRC_BITS) - 1)
#define T_APP 16384         // edges per bappend block
#define NHB 256             // bhist partial blocks
#define PSTRIDE 800         // pcount row stride (>= nb)
#define GPAD 16             // gcur padding (ints) -> 64B per cursor
#define LOG2E 1.4426950408889634f

typedef unsigned int uint;

__device__ __forceinline__ uint f2bf(float f) {
  uint u = __float_as_uint(f);
  return (u + 0x7fffu + ((u >> 16) & 1u)) >> 16;  // RNE
}
__device__ __forceinline__ float bflo(uint u) { return __uint_as_float(u << 16); }
__device__ __forceinline__ float bfhi(uint u) { return __uint_as_float(u & 0xffff0000u); }

// ---------------- lin1: h0 = relu(x @ W1^T + b1) -> bf16 rows ----------------
__global__ __launch_bounds__(256) void lin1_kernel(
    const float* __restrict__ x, const float* __restrict__ w1,
    const float* __restrict__ b1, uint* __restrict__ h0b, int N) {
  __shared__ float sW[16 * F_IN];
  for (int i = threadIdx.x; i < 16 * F_IN / 4; i += 256)
    ((float4*)sW)[i] = ((const float4*)w1)[i];
  __syncthreads();

  int wave = (blockIdx.x * 256 + threadIdx.x) >> 6;
  int lane = threadIdx.x & 63;
  int j = lane & 15;
  int g = lane >> 4;
  int node = wave * 4 + g;
  if (node >= N) return;

  const float4* xr = (const float4*)(x + (size_t)node * F_IN);
  float acc[16];
#pragma unroll
  for (int k = 0; k < 16; ++k) acc[k] = 0.f;

#pragma unroll
  for (int t = 0; t < 8; ++t) {
    float4 xv = xr[t * 16 + j];
#pragma unroll
    for (int k = 0; k < 16; ++k) {
      float4 wv = *(const float4*)&sW[k * F_IN + t * 64 + j * 4];
      acc[k] = fmaf(xv.x, wv.x, fmaf(xv.y, wv.y, fmaf(xv.z, wv.z, fmaf(xv.w, wv.w, acc[k]))));
    }
  }
#pragma unroll
  for (int s = 1; s < 16; s <<= 1) {
#pragma unroll
    for (int k = 0; k < 16; ++k) acc[k] += __shfl_xor(acc[k], s, 64);
  }
  float hv = 0.f;
#pragma unroll
  for (int k = 0; k < 16; ++k)
    if (j == k) hv = acc[k];
  hv += b1[j];
  hv = fmaxf(hv, 0.f);

  float hp = __shfl_xor(hv, 1, 64);  // partner feature (j^1)
  if (!(j & 1))                      // even j packs (j, j+1)
    h0b[(size_t)node * 8 + (j >> 1)] = f2bf(hv) | (f2bf(hp) << 16);
}

// ---------------- edge build (round-9 version, measured good) ----------------
__global__ __launch_bounds__(256) void bhistp_kernel(
    const int* __restrict__ dst, int* __restrict__ pcount, int E, int nb) {
  __shared__ int hist[1024];
  for (int i = threadIdx.x; i < nb; i += 256) hist[i] = 0;
  __syncthreads();
  for (int e = blockIdx.x * 256 + threadIdx.x; e < E; e += NHB * 256)
    atomicAdd(&hist[dst[e] >> 7], 1);
  __syncthreads();
  int* row = pcount + (size_t)blockIdx.x * PSTRIDE;
  for (int i = threadIdx.x; i < nb; i += 256) row[i] = hist[i];
}

__global__ __launch_bounds__(1024) void bscan_kernel(
    const int* __restrict__ pcount, int* __restrict__ boff, int* __restrict__ bcount,
    int* __restrict__ gcur, int* __restrict__ offg, int N, int nb, int E) {
  __shared__ int s[1024];
  int t = threadIdx.x;
  int v = 0;
  if (t < nb) {
#pragma unroll 8
    for (int b = 0; b < NHB; ++b) v += pcount[(size_t)b * PSTRIDE + t];
  }
  s[t] = v;
  __syncthreads();
  for (int st = 1; st < 1024; st <<= 1) {
    int a = (t >= st) ? s[t - st] : 0;
    __syncthreads();
    s[t] += a;
    __syncthreads();
  }
  if (t < nb) {
    int off = s[t] - v;
    boff[t] = off;
    bcount[t] = v;
    gcur[t * GPAD] = off;
  }
  if (t == 0) offg[N] = E;
}

__global__ __launch_bounds__(512) void bappend_kernel(
    const int* __restrict__ src, const int* __restrict__ dst,
    int* __restrict__ gcur, int* __restrict__ elist, int E, int nb) {
  __shared__ int hist[1024], base[1024], curl[1024];
  int t = threadIdx.x;
  int e0 = blockIdx.x * T_APP;
  int e1 = min(E, e0 + T_APP);
  for (int i = t; i < nb; i += 512) hist[i] = 0;
  __syncthreads();
  for (int i = e0 + t; i < e1; i += 512) atomicAdd(&hist[dst[i] >> 7], 1);
  __syncthreads();
  for (int i = t; i < nb; i += 512) {
    int c = hist[i];
    base[i] = c ? atomicAdd(&gcur[i * GPAD], c) : 0;
    curl[i] = 0;
  }
  __syncthreads();
  for (int i = e0 + t; i < e1; i += 512) {
    int d = dst[i];
    int b = d >> 7;
    int slot = base[b] + atomicAdd(&curl[b], 1);
    elist[slot] = src[i] | ((d & (NB - 1)) << SRC_BITS);
  }
}

__global__ __launch_bounds__(256) void bsort_kernel(
    const int* __restrict__ elist, const int* __restrict__ boff,
    const int* __restrict__ bcount, int* __restrict__ csr,
    int* __restrict__ offg, int N) {
  __shared__ int hist[NB], scn[NB], cur[NB];
  int b = blockIdx.x, t = threadIdx.x;
  int base = boff[b], cnt = bcount[b];
  int node0 = b * NB, nn = min(NB, N - node0);
  if (t < NB) hist[t] = 0;
  __syncthreads();
  for (int i = t; i < cnt; i += 256) atomicAdd(&hist[elist[base + i] >> SRC_BITS], 1);
  __syncthreads();
  if (t < NB) scn[t] = hist[t];
  __syncthreads();
  for (int st = 1; st < NB; st <<= 1) {
    int v = (t >= st && t < NB) ? scn[t - st] : 0;
    __syncthreads();
    if (t < NB) scn[t] += v;
    __syncthreads();
  }
  if (t < NB) {
    int ex = scn[t] - hist[t];
    cur[t] = ex;
    if (t < nn) offg[node0 + t] = base + ex;
  }
  __syncthreads();
  for (int i = t; i < cnt; i += 256) {
    int pk = elist[base + i];
    int ld = pk >> SRC_BITS;
    int slot = atomicAdd(&cur[ld], 1);
    csr[base + slot] = pk & SRC_MASK;
  }
}

// ---------------- AGNN propagation: wave per dst node, 16 edge-slots x 4 lanes ----------
// lane = 4*slot + p. Norms derived in-register. Edge loop unrolled x4:
// 4 independent csr->row load chains in flight per iteration (stride 64 edges).
template <bool LAST>
__global__ __launch_bounds__(256) void prop_kernel(
    const uint2* __restrict__ hb, const int* __restrict__ off,
    const int* __restrict__ csr, const float* __restrict__ beta_ptr,
    uint2* __restrict__ houtb, float* __restrict__ hout32, int N) {
  int d = (blockIdx.x * 256 + threadIdx.x) >> 6;
  int lane = threadIdx.x & 63;
  int p = lane & 3;       // feature quad
  int slot = lane >> 2;   // 16 edge slots
  if (d >= N) return;

  float beta = beta_ptr ? beta_ptr[0] : 1.0f;
  uint2 hdu = hb[(size_t)d * 4 + p];
  float hd0 = bflo(hdu.x), hd1 = bfhi(hdu.x), hd2 = bflo(hdu.y), hd3 = bfhi(hdu.y);

  float ssd = fmaf(hd0, hd0, fmaf(hd1, hd1, fmaf(hd2, hd2, hd3 * hd3)));
  ssd += __shfl_xor(ssd, 1, 64);
  ssd += __shfl_xor(ssd, 2, 64);
  float rnd = rsqrtf(fmaxf(ssd, 1e-24f));
  float brnl2d = beta * LOG2E * rnd;

  float den = 0.f, n0 = 0.f, n1 = 0.f, n2 = 0.f, n3 = 0.f;
  if (slot == 0) {
    float es = exp2f(beta * LOG2E);    // self-loop: cos = 1
    den = es;
    n0 = es * hd0; n1 = es * hd1; n2 = es * hd2; n3 = es * hd3;
  }

  int base = off[d];
  int dg = off[d + 1] - base;
  for (int i = slot; i < dg; i += 64) {
    int i1 = i + 16, i2 = i + 32, i3 = i + 48;
    bool v1 = i1 < dg, v2 = i2 < dg, v3 = i3 < dg;
    int s0 = csr[base + i];
    int s1 = v1 ? csr[base + i1] : s0;
    int s2 = v2 ? csr[base + i2] : s0;
    int s3 = v3 ? csr[base + i3] : s0;
    uint2 u0 = hb[(size_t)s0 * 4 + p];
    uint2 u1 = hb[(size_t)s1 * 4 + p];
    uint2 u2 = hb[(size_t)s2 * 4 + p];
    uint2 u3 = hb[(size_t)s3 * 4 + p];

    float a0 = bflo(u0.x), a1 = bfhi(u0.x), a2 = bflo(u0.y), a3 = bfhi(u0.y);
    float b0 = bflo(u1.x), b1 = bfhi(u1.x), b2 = bflo(u1.y), b3 = bfhi(u1.y);
    float c0 = bflo(u2.x), c1 = bfhi(u2.x), c2 = bflo(u2.y), c3 = bfhi(u2.y);
    float d0 = bflo(u3.x), d1 = bfhi(u3.x), d2 = bflo(u3.y), d3 = bfhi(u3.y);

    float dtA = fmaf(a0, hd0, fmaf(a1, hd1, fmaf(a2, hd2, a3 * hd3)));
    float dtB = fmaf(b0, hd0, fmaf(b1, hd1, fmaf(b2, hd2, b3 * hd3)));
    float dtC = fmaf(c0, hd0, fmaf(c1, hd1, fmaf(c2, hd2, c3 * hd3)));
    float dtD = fmaf(d0, hd0, fmaf(d1, hd1, fmaf(d2, hd2, d3 * hd3)));
    float ssA = fmaf(a0, a0, fmaf(a1, a1, fmaf(a2, a2, a3 * a3)));
    float ssB = fmaf(b0, b0, fmaf(b1, b1, fmaf(b2, b2, b3 * b3)));
    float ssC = fmaf(c0, c0, fmaf(c1, c1, fmaf(c2, c2, c3 * c3)));
    float ssD = fmaf(d0, d0, fmaf(d1, d1, fmaf(d2, d2, d3 * d3)));

    dtA += __shfl_xor(dtA, 1, 64); ssA += __shfl_xor(ssA, 1, 64);
    dtB += __shfl_xor(dtB, 1, 64); ssB += __shfl_xor(ssB, 1, 64);
    dtC += __shfl_xor(dtC, 1, 64); ssC += __shfl_xor(ssC, 1, 64);
    dtD += __shfl_xor(dtD, 1, 64); ssD += __shfl_xor(ssD, 1, 64);
    dtA += __shfl_xor(dtA, 2, 64); ssA += __shfl_xor(ssA, 2, 64);
    dtB += __shfl_xor(dtB, 2, 64); ssB += __shfl_xor(ssB, 2, 64);
    dtC += __shfl_xor(dtC, 2, 64); ssC += __shfl_xor(ssC, 2, 64);
    dtD += __shfl_xor(dtD, 2, 64); ssD += __shfl_xor(ssD, 2, 64);

    float eA = exp2f(dtA * rsqrtf(fmaxf(ssA, 1e-24f)) * brnl2d);
    float eB = exp2f(dtB * rsqrtf(fmaxf(ssB, 1e-24f)) * brnl2d);
    float eC = exp2f(dtC * rsqrtf(fmaxf(ssC, 1e-24f)) * brnl2d);
    float eD = exp2f(dtD * rsqrtf(fmaxf(ssD, 1e-24f)) * brnl2d);
    eB = v1 ? eB : 0.f;
    eC = v2 ? eC : 0.f;
    eD = v3 ? eD : 0.f;

    den += (eA + eB) + (eC + eD);
    n0 = fmaf(eD, d0, fmaf(eC, c0, fmaf(eB, b0, fmaf(eA, a0, n0))));
    n1 = fmaf(eD, d1, fmaf(eC, c1, fmaf(eB, b1, fmaf(eA, a1, n1))));
    n2 = fmaf(eD, d2, fmaf(eC, c2, fmaf(eB, b2, fmaf(eA, a2, n2))));
    n3 = fmaf(eD, d3, fmaf(eC, c3, fmaf(eB, b3, fmaf(eA, a3, n3))));
  }
#pragma unroll
  for (int st = 4; st < 64; st <<= 1) {
    den += __shfl_xor(den, st, 64);
    n0 += __shfl_xor(n0, st, 64);
    n1 += __shfl_xor(n1, st, 64);
    n2 += __shfl_xor(n2, st, 64);
    n3 += __shfl_xor(n3, st, 64);
  }
  float inv = 1.f / den;
  float o0 = n0 * inv, o1 = n1 * inv, o2 = n2 * inv, o3 = n3 * inv;

  if (LAST) {
    if (slot == 0)
      *(float4*)&hout32[(size_t)d * 16 + 4 * p] = make_float4(o0, o1, o2, o3);
  } else {
    if (slot == 0) {
      uint2 w;
      w.x = f2bf(o0) | (f2bf(o1) << 16);
      w.y = f2bf(o2) | (f2bf(o3) << 16);
      houtb[(size_t)d * 4 + p] = w;
    }
  }
}

// ---------------- lin2 + log_softmax: one thread per node ----------------
__global__ __launch_bounds__(256) void lin2_kernel(
    const float* __restrict__ h2, const float* __restrict__ w2,
    const float* __restrict__ b2, float* __restrict__ out, int N) {
  __shared__ float sw2[256];  // w2[c*16+m]
  __shared__ float sb2[16];
  if (threadIdx.x < 256) sw2[threadIdx.x] = w2[threadIdx.x];
  if (threadIdx.x < 16) sb2[threadIdx.x] = b2[threadIdx.x];
  __syncthreads();

  int n = blockIdx.x * 256 + threadIdx.x;
  if (n >= N) return;

  float h[16];
  const float4* hr = (const float4*)(h2 + (size_t)n * 16);
#pragma unroll
  for (int q = 0; q < 4; ++q) {
    float4 v = hr[q];
    h[4 * q + 0] = v.x; h[4 * q + 1] = v.y; h[4 * q + 2] = v.z; h[4 * q + 3] = v.w;
  }
  float lg[16], mx = -1e30f;
#pragma unroll
  for (int c = 0; c < 16; ++c) {
    float a = sb2[c];
#pragma unroll
    for (int m = 0; m < 16; ++m) a = fmaf(h[m], sw2[c * 16 + m], a);
    lg[c] = a;
    mx = fmaxf(mx, a);
  }
  float sm = 0.f;
#pragma unroll
  for (int c = 0; c < 16; ++c) sm += __expf(lg[c] - mx);
  float ls = mx + logf(sm);
  float4* orow = (float4*)(out + (size_t)n * 16);
#pragma unroll
  for (int q = 0; q < 4; ++q)
    orow[q] = make_float4(lg[4 * q + 0] - ls, lg[4 * q + 1] - ls,
                          lg[4 * q + 2] - ls, lg[4 * q + 3] - ls);
}

extern "C" void kernel_launch(void* const* d_in, const int* in_sizes, int n_in,
                              void* d_out, int out_size, void* d_ws, size_t ws_size,
                              hipStream_t stream) {
  const float* x     = (const float*)d_in[0];
  const int*   ei    = (const int*)d_in[1];
  const float* w1    = (const float*)d_in[2];
  const float* b1    = (const float*)d_in[3];
  const float* w2    = (const float*)d_in[4];
  const float* b2    = (const float*)d_in[5];
  const float* beta2 = (const float*)d_in[6];
  float* out = (float*)d_out;

  const int N = in_sizes[0] / F_IN;   // 100000
  const int E = in_sizes[1] / 2;      // 3200000
  const int* src = ei;
  const int* dst = ei + E;
  const int nb = (N + NB - 1) / NB;   // 782

  char* ws = (char*)d_ws;
  size_t wo = 0;
  auto take = [&](size_t bytes) -> void* {
    void* p = ws + wo;
    wo = (wo + bytes + 255) & ~(size_t)255;
    return p;
  };
  int*   pcount = (int*)take((size_t)NHB * PSTRIDE * 4);  // per-block partial hists
  int*   bcount = (int*)take((size_t)nb * 4);
  int*   boff   = (int*)take((size_t)nb * 4);
  int*   gcur   = (int*)take((size_t)nb * GPAD * 4);      // padded cursors (64B each)
  int*   offg   = (int*)take((size_t)(N + 1) * 4);
  int*   csr    = (int*)take((size_t)E * 4);
  int*   elist  = (int*)take((size_t)E * 4);   // dead after bsort; h1b aliases it
  uint*  h0b    = (uint*)take((size_t)N * 8 * 4);
  float* h2     = (float*)take((size_t)N * 16 * 4);
  uint*  h1b    = (uint*)(elist);              // alias (elist dead before prop1)

  lin1_kernel<<<(N + 15) / 16, 256, 0, stream>>>(x, w1, b1, h0b, N);

  bhistp_kernel<<<NHB, 256, 0, stream>>>(dst, pcount, E, nb);
  bscan_kernel<<<1, 1024, 0, stream>>>(pcount, boff, bcount, gcur, offg, N, nb, E);
  bappend_kernel<<<(E + T_APP - 1) / T_APP, 512, 0, stream>>>(src, dst, gcur, elist, E, nb);
  bsort_kernel<<<nb, 256, 0, stream>>>(elist, boff, bcount, csr, offg, N);

  prop_kernel<false><<<(N + 3) / 4, 256, 0, stream>>>(
      (const uint2*)h0b, offg, csr, nullptr, (uint2*)h1b, nullptr, N);
  prop_kernel<true><<<(N + 3) / 4, 256, 0, stream>>>(
      (const uint2*)h1b, offg, csr, beta2, nullptr, h2, N);
  lin2_kernel<<<(N + 255) / 256, 256, 0, stream>>>(h2, w2, b2, out, N);
}

// Round 12
// 258.202 us; speedup vs baseline: 1.1061x; 1.0465x over previous
//
#include <hip/hip_runtime.h>
#include <hip/hip_bf16.h>

#define F_IN 512
#define NB 128              // dst nodes per bucket
#define SRC_BITS 17         // N <= 131072
#define SRC_MASK ((1 << SRC_BITS) - 1)
#define T_APP 16384         // edges per bappend block
#define NHB 256             // bhist partial blocks
#define PSTRIDE 800         // pcount row stride (>= nb)
#define GPAD 16             // gcur padding (ints) -> 64B per cursor
#define LOG2E 1.4426950408889634f

typedef unsigned int uint;

__device__ __forceinline__ uint f2bf(float f) {
  uint u = __float_as_uint(f);
  return (u + 0x7fffu + ((u >> 16) & 1u)) >> 16;  // RNE
}
__device__ __forceinline__ float bflo(uint u) { return __uint_as_float(u << 16); }
__device__ __forceinline__ float bfhi(uint u) { return __uint_as_float(u & 0xffff0000u); }

// ---------------- lin1: h0 = relu(x @ W1^T + b1) -> bf16 rows ----------------
__global__ __launch_bounds__(256) void lin1_kernel(
    const float* __restrict__ x, const float* __restrict__ w1,
    const float* __restrict__ b1, uint* __restrict__ h0b, int N) {
  __shared__ float sW[16 * F_IN];
  for (int i = threadIdx.x; i < 16 * F_IN / 4; i += 256)
    ((float4*)sW)[i] = ((const float4*)w1)[i];
  __syncthreads();

  int wave = (blockIdx.x * 256 + threadIdx.x) >> 6;
  int lane = threadIdx.x & 63;
  int j = lane & 15;
  int g = lane >> 4;
  int node = wave * 4 + g;
  if (node >= N) return;

  const float4* xr = (const float4*)(x + (size_t)node * F_IN);
  float acc[16];
#pragma unroll
  for (int k = 0; k < 16; ++k) acc[k] = 0.f;

#pragma unroll
  for (int t = 0; t < 8; ++t) {
    float4 xv = xr[t * 16 + j];
#pragma unroll
    for (int k = 0; k < 16; ++k) {
      float4 wv = *(const float4*)&sW[k * F_IN + t * 64 + j * 4];
      acc[k] = fmaf(xv.x, wv.x, fmaf(xv.y, wv.y, fmaf(xv.z, wv.z, fmaf(xv.w, wv.w, acc[k]))));
    }
  }
#pragma unroll
  for (int s = 1; s < 16; s <<= 1) {
#pragma unroll
    for (int k = 0; k < 16; ++k) acc[k] += __shfl_xor(acc[k], s, 64);
  }
  float hv = 0.f;
#pragma unroll
  for (int k = 0; k < 16; ++k)
    if (j == k) hv = acc[k];
  hv += b1[j];
  hv = fmaxf(hv, 0.f);

  float hp = __shfl_xor(hv, 1, 64);  // partner feature (j^1)
  if (!(j & 1))                      // even j packs (j, j+1)
    h0b[(size_t)node * 8 + (j >> 1)] = f2bf(hv) | (f2bf(hp) << 16);
}

// ---------------- edge build ----------------
__global__ __launch_bounds__(256) void bhistp_kernel(
    const int* __restrict__ dst, int* __restrict__ pcount, int E, int nb) {
  __shared__ int hist[1024];
  for (int i = threadIdx.x; i < nb; i += 256) hist[i] = 0;
  __syncthreads();
  for (int e = blockIdx.x * 256 + threadIdx.x; e < E; e += NHB * 256)
    atomicAdd(&hist[dst[e] >> 7], 1);
  __syncthreads();
  int* row = pcount + (size_t)blockIdx.x * PSTRIDE;
  for (int i = threadIdx.x; i < nb; i += 256) row[i] = hist[i];
}

// Parallel partial-sum of the 256 chunk rows -> 8 rows (fully coalesced, no atomics).
__global__ __launch_bounds__(1024) void bsum_kernel(
    const int* __restrict__ pcount, int* __restrict__ bsum8, int nb) {
  int t = threadIdx.x;
  int k = blockIdx.x;  // 8 blocks
  if (t < nb) {
    int v = 0;
#pragma unroll
    for (int j = 0; j < NHB / 8; ++j)
      v += pcount[(size_t)(k * (NHB / 8) + j) * PSTRIDE + t];
    bsum8[k * PSTRIDE + t] = v;
  }
}

__global__ __launch_bounds__(1024) void bscan_kernel(
    const int* __restrict__ bsum8, int* __restrict__ boff, int* __restrict__ bcount,
    int* __restrict__ gcur, int* __restrict__ offg, int N, int nb, int E) {
  __shared__ int s[1024];
  int t = threadIdx.x;
  int v = 0;
  if (t < nb) {
#pragma unroll
    for (int k = 0; k < 8; ++k) v += bsum8[k * PSTRIDE + t];
  }
  s[t] = v;
  __syncthreads();
  for (int st = 1; st < 1024; st <<= 1) {
    int a = (t >= st) ? s[t - st] : 0;
    __syncthreads();
    s[t] += a;
    __syncthreads();
  }
  if (t < nb) {
    int off = s[t] - v;
    boff[t] = off;
    bcount[t] = v;
    gcur[t * GPAD] = off;
  }
  if (t == 0) offg[N] = E;
}

__global__ __launch_bounds__(512) void bappend_kernel(
    const int* __restrict__ src, const int* __restrict__ dst,
    int* __restrict__ gcur, int* __restrict__ elist, int E, int nb) {
  __shared__ int hist[1024], base[1024], curl[1024];
  int t = threadIdx.x;
  int e0 = blockIdx.x * T_APP;
  int e1 = min(E, e0 + T_APP);
  for (int i = t; i < nb; i += 512) hist[i] = 0;
  __syncthreads();
  for (int i = e0 + t; i < e1; i += 512) atomicAdd(&hist[dst[i] >> 7], 1);
  __syncthreads();
  for (int i = t; i < nb; i += 512) {
    int c = hist[i];
    base[i] = c ? atomicAdd(&gcur[i * GPAD], c) : 0;
    curl[i] = 0;
  }
  __syncthreads();
  for (int i = e0 + t; i < e1; i += 512) {
    int d = dst[i];
    int b = d >> 7;
    int slot = base[b] + atomicAdd(&curl[b], 1);
    elist[slot] = src[i] | ((d & (NB - 1)) << SRC_BITS);
  }
}

__global__ __launch_bounds__(256) void bsort_kernel(
    const int* __restrict__ elist, const int* __restrict__ boff,
    const int* __restrict__ bcount, int* __restrict__ csr,
    int* __restrict__ offg, int N) {
  __shared__ int hist[NB], scn[NB], cur[NB];
  int b = blockIdx.x, t = threadIdx.x;
  int base = boff[b], cnt = bcount[b];
  int node0 = b * NB, nn = min(NB, N - node0);
  if (t < NB) hist[t] = 0;
  __syncthreads();
  for (int i = t; i < cnt; i += 256) atomicAdd(&hist[elist[base + i] >> SRC_BITS], 1);
  __syncthreads();
  if (t < NB) scn[t] = hist[t];
  __syncthreads();
  for (int st = 1; st < NB; st <<= 1) {
    int v = (t >= st && t < NB) ? scn[t - st] : 0;
    __syncthreads();
    if (t < NB) scn[t] += v;
    __syncthreads();
  }
  if (t < NB) {
    int ex = scn[t] - hist[t];
    cur[t] = ex;
    if (t < nn) offg[node0 + t] = base + ex;
  }
  __syncthreads();
  for (int i = t; i < cnt; i += 256) {
    int pk = elist[base + i];
    int ld = pk >> SRC_BITS;
    int slot = atomicAdd(&cur[ld], 1);
    csr[base + slot] = pk & SRC_MASK;
  }
}

// ---------------- AGNN propagation: wave per dst node, 16 edge-slots x 4 lanes ----------
// (round-9 version: 2 independent load streams, 32 edges/iteration)
template <bool LAST>
__global__ __launch_bounds__(256) void prop_kernel(
    const uint2* __restrict__ hb, const int* __restrict__ off,
    const int* __restrict__ csr, const float* __restrict__ beta_ptr,
    uint2* __restrict__ houtb, float* __restrict__ hout32, int N) {
  int d = (blockIdx.x * 256 + threadIdx.x) >> 6;
  int lane = threadIdx.x & 63;
  int p = lane & 3;       // feature quad
  int slot = lane >> 2;   // 16 edge slots
  if (d >= N) return;

  float beta = beta_ptr ? beta_ptr[0] : 1.0f;
  uint2 hdu = hb[(size_t)d * 4 + p];
  float hd0 = bflo(hdu.x), hd1 = bfhi(hdu.x), hd2 = bflo(hdu.y), hd3 = bfhi(hdu.y);

  float ssd = fmaf(hd0, hd0, fmaf(hd1, hd1, fmaf(hd2, hd2, hd3 * hd3)));
  ssd += __shfl_xor(ssd, 1, 64);
  ssd += __shfl_xor(ssd, 2, 64);
  float rnd = rsqrtf(fmaxf(ssd, 1e-24f));
  float brnl2d = beta * LOG2E * rnd;

  float den = 0.f, n0 = 0.f, n1 = 0.f, n2 = 0.f, n3 = 0.f;
  if (slot == 0) {
    float es = exp2f(beta * LOG2E);    // self-loop: cos = 1
    den = es;
    n0 = es * hd0; n1 = es * hd1; n2 = es * hd2; n3 = es * hd3;
  }

  int base = off[d];
  int dg = off[d + 1] - base;
  for (int i = slot; i < dg; i += 32) {
    int i1 = i + 16;
    bool v1 = i1 < dg;
    int s0 = csr[base + i];
    int s1 = v1 ? csr[base + i1] : s0;
    uint2 au = hb[(size_t)s0 * 4 + p];
    uint2 bu = hb[(size_t)s1 * 4 + p];
    float a0 = bflo(au.x), a1 = bfhi(au.x), a2 = bflo(au.y), a3 = bfhi(au.y);
    float c0 = bflo(bu.x), c1 = bfhi(bu.x), c2 = bflo(bu.y), c3 = bfhi(bu.y);
    float dt0 = fmaf(a0, hd0, fmaf(a1, hd1, fmaf(a2, hd2, a3 * hd3)));
    float dt1 = fmaf(c0, hd0, fmaf(c1, hd1, fmaf(c2, hd2, c3 * hd3)));
    float ss0 = fmaf(a0, a0, fmaf(a1, a1, fmaf(a2, a2, a3 * a3)));
    float ss1 = fmaf(c0, c0, fmaf(c1, c1, fmaf(c2, c2, c3 * c3)));
    dt0 += __shfl_xor(dt0, 1, 64);
    dt1 += __shfl_xor(dt1, 1, 64);
    ss0 += __shfl_xor(ss0, 1, 64);
    ss1 += __shfl_xor(ss1, 1, 64);
    dt0 += __shfl_xor(dt0, 2, 64);
    dt1 += __shfl_xor(dt1, 2, 64);
    ss0 += __shfl_xor(ss0, 2, 64);
    ss1 += __shfl_xor(ss1, 2, 64);
    float rs0 = rsqrtf(fmaxf(ss0, 1e-24f));
    float rs1 = rsqrtf(fmaxf(ss1, 1e-24f));
    float e0 = exp2f(dt0 * rs0 * brnl2d);
    float e1 = exp2f(dt1 * rs1 * brnl2d);
    e1 = v1 ? e1 : 0.f;
    den += e0 + e1;
    n0 = fmaf(e1, c0, fmaf(e0, a0, n0));
    n1 = fmaf(e1, c1, fmaf(e0, a1, n1));
    n2 = fmaf(e1, c2, fmaf(e0, a2, n2));
    n3 = fmaf(e1, c3, fmaf(e0, a3, n3));
  }
#pragma unroll
  for (int st = 4; st < 64; st <<= 1) {
    den += __shfl_xor(den, st, 64);
    n0 += __shfl_xor(n0, st, 64);
    n1 += __shfl_xor(n1, st, 64);
    n2 += __shfl_xor(n2, st, 64);
    n3 += __shfl_xor(n3, st, 64);
  }
  float inv = 1.f / den;
  float o0 = n0 * inv, o1 = n1 * inv, o2 = n2 * inv, o3 = n3 * inv;

  if (LAST) {
    if (slot == 0)
      *(float4*)&hout32[(size_t)d * 16 + 4 * p] = make_float4(o0, o1, o2, o3);
  } else {
    if (slot == 0) {
      uint2 w;
      w.x = f2bf(o0) | (f2bf(o1) << 16);
      w.y = f2bf(o2) | (f2bf(o3) << 16);
      houtb[(size_t)d * 4 + p] = w;
    }
  }
}

// ---------------- lin2 + log_softmax: one thread per node ----------------
__global__ __launch_bounds__(256) void lin2_kernel(
    const float* __restrict__ h2, const float* __restrict__ w2,
    const float* __restrict__ b2, float* __restrict__ out, int N) {
  __shared__ float sw2[256];  // w2[c*16+m]
  __shared__ float sb2[16];
  if (threadIdx.x < 256) sw2[threadIdx.x] = w2[threadIdx.x];
  if (threadIdx.x < 16) sb2[threadIdx.x] = b2[threadIdx.x];
  __syncthreads();

  int n = blockIdx.x * 256 + threadIdx.x;
  if (n >= N) return;

  float h[16];
  const float4* hr = (const float4*)(h2 + (size_t)n * 16);
#pragma unroll
  for (int q = 0; q < 4; ++q) {
    float4 v = hr[q];
    h[4 * q + 0] = v.x; h[4 * q + 1] = v.y; h[4 * q + 2] = v.z; h[4 * q + 3] = v.w;
  }
  float lg[16], mx = -1e30f;
#pragma unroll
  for (int c = 0; c < 16; ++c) {
    float a = sb2[c];
#pragma unroll
    for (int m = 0; m < 16; ++m) a = fmaf(h[m], sw2[c * 16 + m], a);
    lg[c] = a;
    mx = fmaxf(mx, a);
  }
  float sm = 0.f;
#pragma unroll
  for (int c = 0; c < 16; ++c) sm += __expf(lg[c] - mx);
  float ls = mx + logf(sm);
  float4* orow = (float4*)(out + (size_t)n * 16);
#pragma unroll
  for (int q = 0; q < 4; ++q)
    orow[q] = make_float4(lg[4 * q + 0] - ls, lg[4 * q + 1] - ls,
                          lg[4 * q + 2] - ls, lg[4 * q + 3] - ls);
}

extern "C" void kernel_launch(void* const* d_in, const int* in_sizes, int n_in,
                              void* d_out, int out_size, void* d_ws, size_t ws_size,
                              hipStream_t stream) {
  const float* x     = (const float*)d_in[0];
  const int*   ei    = (const int*)d_in[1];
  const float* w1    = (const float*)d_in[2];
  const float* b1    = (const float*)d_in[3];
  const float* w2    = (const float*)d_in[4];
  const float* b2    = (const float*)d_in[5];
  const float* beta2 = (const float*)d_in[6];
  float* out = (float*)d_out;

  const int N = in_sizes[0] / F_IN;   // 100000
  const int E = in_sizes[1] / 2;      // 3200000
  const int* src = ei;
  const int* dst = ei + E;
  const int nb = (N + NB - 1) / NB;   // 782

  char* ws = (char*)d_ws;
  size_t wo = 0;
  auto take = [&](size_t bytes) -> void* {
    void* p = ws + wo;
    wo = (wo + bytes + 255) & ~(size_t)255;
    return p;
  };
  int*   pcount = (int*)take((size_t)NHB * PSTRIDE * 4);  // per-block partial hists
  int*   bsum8  = (int*)take((size_t)8 * PSTRIDE * 4);
  int*   bcount = (int*)take((size_t)nb * 4);
  int*   boff   = (int*)take((size_t)nb * 4);
  int*   gcur   = (int*)take((size_t)nb * GPAD * 4);      // padded cursors (64B each)
  int*   offg   = (int*)take((size_t)(N + 1) * 4);
  int*   csr    = (int*)take((size_t)E * 4);
  int*   elist  = (int*)take((size_t)E * 4);   // dead after bsort; h1b aliases it
  uint*  h0b    = (uint*)take((size_t)N * 8 * 4);
  float* h2     = (float*)take((size_t)N * 16 * 4);
  uint*  h1b    = (uint*)(elist);              // alias (elist dead before prop1)

  lin1_kernel<<<(N + 15) / 16, 256, 0, stream>>>(x, w1, b1, h0b, N);

  bhistp_kernel<<<NHB, 256, 0, stream>>>(dst, pcount, E, nb);
  bsum_kernel<<<8, 1024, 0, stream>>>(pcount, bsum8, nb);
  bscan_kernel<<<1, 1024, 0, stream>>>(bsum8, boff, bcount, gcur, offg, N, nb, E);
  bappend_kernel<<<(E + T_APP - 1) / T_APP, 512, 0, stream>>>(src, dst, gcur, elist, E, nb);
  bsort_kernel<<<nb, 256, 0, stream>>>(elist, boff, bcount, csr, offg, N);

  prop_kernel<false><<<(N + 3) / 4, 256, 0, stream>>>(
      (const uint2*)h0b, offg, csr, nullptr, (uint2*)h1b, nullptr, N);
  prop_kernel<true><<<(N + 3) / 4, 256, 0, stream>>>(
      (const uint2*)h1b, offg, csr, beta2, nullptr, h2, N);
  lin2_kernel<<<(N + 255) / 256, 256, 0, stream>>>(h2, w2, b2, out, N);
}